// Round 13
// baseline (771.000 us; speedup 1.0000x reference)
//
#include <hip/hip_runtime.h>
#include <math.h>

#define BB 4
#define SS 2048
#define NH 8
#define HD 64
#define HID 512
#define EPSV 1e-5f

#define NROWS (BB * SS)                // 8192 (b,s) rows
#define QKV_ELEMS (BB * NH * SS * HD)  // 4,194,304
#define TOTROWS (BB * NH * SS)         // 65536 (b,h,s) rows
#define NJT 16                         // msnap granularity: 128-wide jtiles

typedef __attribute__((ext_vector_type(8))) short short8;
typedef __attribute__((ext_vector_type(4))) float f32x4;

__device__ __forceinline__ unsigned short f2h(float f) {
  _Float16 h = (_Float16)f;
  return __builtin_bit_cast(unsigned short, h);
}
__device__ __forceinline__ float h2f(unsigned short u) {
  return (float)__builtin_bit_cast(_Float16, u);
}

// SAD of 2 packed u16 with accumulate: acc += |a.h0-b.h0| + |a.h1-b.h1|.
// Q/K are u16 fixed-point: u = round((x+8)*4096); offsets cancel in the
// subtraction so acc = 4096 * sum|q-k| exactly.
__device__ __forceinline__ void sad2(unsigned qa, unsigned kb, unsigned& acc) {
  asm("v_sad_u16 %0, %1, %2, %0" : "+v"(acc) : "v"(qa), "v"(kb));
}

__device__ __forceinline__ unsigned pk_mul_f16(unsigned a, unsigned b) {
  unsigned r;
  asm("v_pk_mul_f16 %0, %1, %2" : "=v"(r) : "v"(a), "v"(b));
  return r;
}

// ---------------------------------------------------------------------------
// f16-MFMA GEMM: C = A(M x 512) @ W(512 x 512)^T + bias.
// 128x128 tile, 256 threads (4 waves, 2x2 quadrants of 64x64), K-step 32.
// AF16: A is f16 (ushort) in gmem; else f32 (converted during staging).
// MODE 0: C f32 [m][n].
// MODE 2: C f16 transposed per head [bh][d][s] (V -> PV B-operand).
// MODE 3: C u16 FIXED-POINT split-head [bh][s][d] (Q, K for SAD scores):
//         u = clamp(round((v + 8) * 4096), 0, 65535).
// ---------------------------------------------------------------------------
template <int MODE, bool AF16>
__global__ __launch_bounds__(256, 2) void gemm_f16(const void* __restrict__ Ain,
                                                   const float* __restrict__ W,
                                                   const float* __restrict__ bias,
                                                   void* __restrict__ Cout) {
  __shared__ unsigned short As[128][40];  // 32 k + 8 pad
  __shared__ unsigned short Ws[128][40];
  const int m0 = blockIdx.y * 128;
  const int n0 = blockIdx.x * 128;
  const int tid = threadIdx.x;
  const int lane = tid & 63;
  const int w = tid >> 6;
  const int wr = w >> 1;
  const int wc = w & 1;
  const int l16 = lane & 15;
  const int lq = lane >> 4;

  f32x4 acc[4][4];
#pragma unroll
  for (int mr = 0; mr < 4; ++mr)
#pragma unroll
    for (int nc = 0; nc < 4; ++nc) acc[mr][nc] = (f32x4)0.f;

  for (int k0 = 0; k0 < HID; k0 += 32) {
    __syncthreads();
    if (AF16) {
      const unsigned short* A = (const unsigned short*)Ain;
#pragma unroll
      for (int p = 0; p < 2; ++p) {
        int idx = tid + p * 256;
        int row = idx >> 2;
        int ch = (idx & 3) * 8;
        *(uint4*)&As[row][ch] = *(const uint4*)&A[(size_t)(m0 + row) * HID + k0 + ch];
      }
#pragma unroll
      for (int p = 0; p < 4; ++p) {
        int idx = tid + p * 256;
        int row = idx >> 3;
        int c4 = (idx & 7) * 4;
        float4 wv = *(const float4*)&W[(size_t)(n0 + row) * HID + k0 + c4];
        ushort4 wb = {f2h(wv.x), f2h(wv.y), f2h(wv.z), f2h(wv.w)};
        *(ushort4*)&Ws[row][c4] = wb;
      }
    } else {
      const float* A = (const float*)Ain;
#pragma unroll
      for (int p = 0; p < 4; ++p) {
        int idx = tid + p * 256;
        int row = idx >> 3;
        int c4 = (idx & 7) * 4;
        float4 av = *(const float4*)&A[(size_t)(m0 + row) * HID + k0 + c4];
        float4 wv = *(const float4*)&W[(size_t)(n0 + row) * HID + k0 + c4];
        ushort4 ab = {f2h(av.x), f2h(av.y), f2h(av.z), f2h(av.w)};
        ushort4 wb = {f2h(wv.x), f2h(wv.y), f2h(wv.z), f2h(wv.w)};
        *(ushort4*)&As[row][c4] = ab;
        *(ushort4*)&Ws[row][c4] = wb;
      }
    }
    __syncthreads();
    const int kb = lq * 8;
    short8 a[4], b[4];
#pragma unroll
    for (int mr = 0; mr < 4; ++mr)
      a[mr] = *(const short8*)&As[wr * 64 + mr * 16 + l16][kb];
#pragma unroll
    for (int nc = 0; nc < 4; ++nc)
      b[nc] = *(const short8*)&Ws[wc * 64 + nc * 16 + l16][kb];
#pragma unroll
    for (int mr = 0; mr < 4; ++mr)
#pragma unroll
      for (int nc = 0; nc < 4; ++nc)
        acc[mr][nc] = __builtin_amdgcn_mfma_f32_16x16x32_f16(a[mr], b[nc], acc[mr][nc], 0, 0, 0);
  }

#pragma unroll
  for (int nc = 0; nc < 4; ++nc) {
    const int n = n0 + wc * 64 + nc * 16 + l16;
    const float bv = bias[n];
#pragma unroll
    for (int mr = 0; mr < 4; ++mr) {
#pragma unroll
      for (int jj = 0; jj < 4; ++jj) {
        const int m = m0 + wr * 64 + mr * 16 + lq * 4 + jj;
        float v = acc[mr][nc][jj] + bv;
        if (MODE == 0) {
          ((float*)Cout)[(size_t)m * HID + n] = v;
        } else if (MODE == 2) {  // f16 [bh][d][s]
          const int b_ = m >> 11, s = m & (SS - 1);
          const int h = n >> 6, d = n & 63;
          ((unsigned short*)Cout)[(((size_t)(b_ * NH + h)) * HD + d) * SS + s] = f2h(v);
        } else {  // MODE 3: u16 fixed-point [bh][s][d]
          const int b_ = m >> 11, s = m & (SS - 1);
          const int h = n >> 6, d = n & 63;
          int u = (int)floorf(fmaf(v, 4096.f, 32768.5f));
          u = u < 0 ? 0 : (u > 65535 ? 65535 : u);
          ((unsigned short*)Cout)[(((size_t)(b_ * NH + h)) * SS + s) * HD + d] =
              (unsigned short)u;
        }
      }
    }
  }
}

// ---------------------------------------------------------------------------
// Scores pass: 128-row i-tile, 128-col j-tiles, 512 threads (8 waves).
// 4x8 micro-tile: thread (trow=tid>>4, cg=tid&15) owns rows
// {i0+trow+32*rr, rr=0..3}, cols {cg+16c, c=0..7}. Each kx LDS read feeds
// 16 SADs (was 8) -> total LDS instructions halve vs the 2-row version.
// Q streamed from global/L1 with fully-static indexing (no remat/scratch).
// Writes p' = exp(s - m_running) f16 into the SECOND HALF of each attn row.
// ---------------------------------------------------------------------------
__global__ __launch_bounds__(512, 4) void scores_kernel(
    const unsigned short* __restrict__ Qh, const unsigned short* __restrict__ Kh,
    const int* __restrict__ mask, const float* __restrict__ temp,
    float* __restrict__ attn, float* __restrict__ stats,
    float* __restrict__ msnap) {
  __shared__ unsigned short Ks[128][72];  // 64 u16 + 8 pad (144B rows)
  __shared__ int Ms[128];

  const int bh = blockIdx.y;
  const int b = bh >> 3;
  const int h = bh & 7;
  const int i0 = blockIdx.x * 128;
  const int tid = threadIdx.x;
  const int trow = tid >> 4;  // 0..31
  const int cg = tid & 15;    // 0..15
  const float tscale = temp[h] * (1.0f / 4096.0f);  // dist = sad * 2^-12

  const unsigned short* Qb = Qh + (size_t)bh * SS * HD;
  const unsigned short* Kb = Kh + (size_t)bh * SS * HD;
  float* attn_b = attn + (size_t)bh * SS * SS;

  // Q rows (4 x 8 uint4), fully static indexing; compiler streams from L1.
  uint4 q[4][8];
#pragma unroll
  for (int rr = 0; rr < 4; ++rr)
#pragma unroll
    for (int k8 = 0; k8 < 8; ++k8)
      q[rr][k8] = *(const uint4*)&Qb[(size_t)(i0 + trow + 32 * rr) * HD + k8 * 8];

  float m[4], sg[4];
#pragma unroll
  for (int rr = 0; rr < 4; ++rr) {
    m[rr] = -INFINITY;
    sg[rr] = 0.f;
  }

  for (int j0 = 0; j0 < SS; j0 += 128) {
    __syncthreads();  // protect Ks reads from previous iteration
// stage K tile: 128 x 64 u16 = 1024 uint4 chunks (2 per thread)
#pragma unroll
    for (int p = 0; p < 2; ++p) {
      int idx = tid + p * 512;
      int row = idx >> 3;
      int ch = (idx & 7) * 8;
      *(uint4*)&Ks[row][ch] = *(const uint4*)&Kb[(size_t)(j0 + row) * HD + ch];
    }
    if (tid < 128) Ms[tid] = mask[b * SS + j0 + tid];
    __syncthreads();

    unsigned d[4][8];
#pragma unroll
    for (int rr = 0; rr < 4; ++rr)
#pragma unroll
      for (int c = 0; c < 8; ++c) d[rr][c] = 0u;

// fully static unroll; 1 kx LDS read feeds 16 SADs (4 rows x 4 dwords).
#pragma unroll
    for (int k8 = 0; k8 < 8; ++k8) {
#pragma unroll
      for (int c = 0; c < 8; ++c) {
        const uint4 kx = *(const uint4*)&Ks[cg + 16 * c][k8 * 8];
#pragma unroll
        for (int rr = 0; rr < 4; ++rr) {
          sad2(q[rr][k8].x, kx.x, d[rr][c]);
          sad2(q[rr][k8].y, kx.y, d[rr][c]);
          sad2(q[rr][k8].z, kx.z, d[rr][c]);
          sad2(q[rr][k8].w, kx.w, d[rr][c]);
        }
      }
    }

    int msk[8];
#pragma unroll
    for (int c = 0; c < 8; ++c) msk[c] = Ms[cg + 16 * c];

    const int jt = j0 >> 7;
#pragma unroll
    for (int rr = 0; rr < 4; ++rr) {
      float s[8];
      float rmax = -INFINITY;
#pragma unroll
      for (int c = 0; c < 8; ++c) {
        float sc = -(float)d[rr][c] * tscale;
        if (msk[c] == 0) sc = -1e9f;
        s[c] = sc;
        rmax = fmaxf(rmax, sc);
      }
// make row max uniform across the 16 cg lanes
#pragma unroll
      for (int off = 1; off < 16; off <<= 1) rmax = fmaxf(rmax, __shfl_xor(rmax, off));
      const float mnew = fmaxf(m[rr], rmax);
      const int i = i0 + trow + 32 * rr;
      unsigned short* arow = (unsigned short*)(attn_b + (size_t)i * SS);
      float psum = 0.f;
#pragma unroll
      for (int c = 0; c < 8; ++c) {
        float pv = __expf(s[c] - mnew);
        psum += pv;
        arow[2048 + j0 + cg + 16 * c] = f2h(pv);  // p' f16, 2nd half of row
      }
      sg[rr] = sg[rr] * __expf(m[rr] - mnew) + psum;
      m[rr] = mnew;
      if (cg == 0) msnap[((size_t)bh * NJT + jt) * SS + i] = mnew;
    }
  }

#pragma unroll
  for (int rr = 0; rr < 4; ++rr) {
    float ssum = sg[rr];
#pragma unroll
    for (int off = 1; off < 16; off <<= 1) ssum += __shfl_xor(ssum, off);
    if (cg == 0) {
      const int row = bh * SS + i0 + trow + 32 * rr;
      stats[2 * row] = m[rr];
      stats[2 * row + 1] = ssum;
    }
  }
}

// ---------------------------------------------------------------------------
// FUSED pv+norm: per j-tile, read p' f16 (from 2nd half of each attn row),
// p32 = h2f(p') * corr -> write final f32 attn columns in place;
// p16 = pk_mul(p', corr_f16) -> Ps for the PV MFMA -> aout f16.
// ---------------------------------------------------------------------------
__global__ __launch_bounds__(256, 4) void attn_pv_norm_kernel(
    const unsigned short* __restrict__ Vt, const float* __restrict__ stats,
    const float* __restrict__ msnap, float* __restrict__ attn,
    unsigned short* __restrict__ attn_out) {
  __shared__ unsigned short Ps[64][72];
  __shared__ unsigned short Vts[64][72];
  __shared__ float corr_s[64];

  const int bh = blockIdx.y;
  const int b = bh >> 3;
  const int h = bh & 7;
  const int i0 = blockIdx.x * 64;
  const int tid = threadIdx.x;
  const int lane = tid & 63;
  const int w = tid >> 6;
  const int wr = w >> 1;
  const int wc = w & 1;
  const int l16 = lane & 15;
  const int lq = lane >> 4;

  float* attn_b = attn + (size_t)bh * SS * SS;
  const unsigned short* Vtb = Vt + (size_t)bh * HD * SS;

  float mfin = 0.f, inv = 0.f;
  if (tid < 64) {
    const int row = bh * SS + i0 + tid;
    mfin = stats[2 * row];
    inv = 1.0f / stats[2 * row + 1];
  }

  f32x4 acc[2][2];
#pragma unroll
  for (int mr = 0; mr < 2; ++mr)
#pragma unroll
    for (int nc = 0; nc < 2; ++nc) acc[mr][nc] = (f32x4)0.f;

  for (int j0 = 0; j0 < SS; j0 += 64) {
    __syncthreads();  // protect prev-iter Ps/Vts reads
    if (tid < 64)
      corr_s[tid] =
          __expf(msnap[((size_t)bh * NJT + (j0 >> 7)) * SS + i0 + tid] - mfin) * inv;
    // stage Vt tile + issue p' loads (p' lives at ushort offset 2048+)
    uint4 pv[2];
#pragma unroll
    for (int p = 0; p < 2; ++p) {
      int idx = tid + p * 256;
      int row = idx >> 3;
      int ch = (idx & 7) * 8;
      *(uint4*)&Vts[row][ch] = *(const uint4*)&Vtb[(size_t)row * SS + j0 + ch];
      pv[p] = *(const uint4*)((const unsigned short*)(attn_b + (size_t)(i0 + row) * SS) +
                              2048 + j0 + ch);
    }
    __syncthreads();  // corr_s ready; all p' loads drained before f32 stores
// p16 = p' * corr (packed f16) -> Ps ; p32 = h2f(p') * corr -> attn f32
#pragma unroll
    for (int p = 0; p < 2; ++p) {
      int idx = tid + p * 256;
      int row = idx >> 3;
      int ch = (idx & 7) * 8;
      const float cr = corr_s[row];
      unsigned short cu = f2h(cr);
      unsigned c2 = (unsigned)cu | ((unsigned)cu << 16);
      uint4 r;
      r.x = pk_mul_f16(pv[p].x, c2);
      r.y = pk_mul_f16(pv[p].y, c2);
      r.z = pk_mul_f16(pv[p].z, c2);
      r.w = pk_mul_f16(pv[p].w, c2);
      *(uint4*)&Ps[row][ch] = r;
      float* orow = attn_b + (size_t)(i0 + row) * SS + j0 + ch;
      float4 o0 = {h2f((unsigned short)(pv[p].x)) * cr,
                   h2f((unsigned short)(pv[p].x >> 16)) * cr,
                   h2f((unsigned short)(pv[p].y)) * cr,
                   h2f((unsigned short)(pv[p].y >> 16)) * cr};
      float4 o1 = {h2f((unsigned short)(pv[p].z)) * cr,
                   h2f((unsigned short)(pv[p].z >> 16)) * cr,
                   h2f((unsigned short)(pv[p].w)) * cr,
                   h2f((unsigned short)(pv[p].w >> 16)) * cr};
      *(float4*)&orow[0] = o0;
      *(float4*)&orow[4] = o1;
    }
    __syncthreads();
// MFMA: out(64x64) += P(64x64) @ V(64x64)
#pragma unroll
    for (int ks = 0; ks < 2; ++ks) {
      const int kb = ks * 32 + lq * 8;
      short8 a[2], bf[2];
#pragma unroll
      for (int mr = 0; mr < 2; ++mr)
        a[mr] = *(const short8*)&Ps[wr * 32 + mr * 16 + l16][kb];
#pragma unroll
      for (int nc = 0; nc < 2; ++nc)
        bf[nc] = *(const short8*)&Vts[wc * 32 + nc * 16 + l16][kb];
#pragma unroll
      for (int mr = 0; mr < 2; ++mr)
#pragma unroll
        for (int nc = 0; nc < 2; ++nc)
          acc[mr][nc] = __builtin_amdgcn_mfma_f32_16x16x32_f16(a[mr], bf[nc], acc[mr][nc], 0, 0, 0);
    }
  }

// epilogue: f16 write [b, s, h*64 + d]
#pragma unroll
  for (int mr = 0; mr < 2; ++mr)
#pragma unroll
    for (int nc = 0; nc < 2; ++nc)
#pragma unroll
      for (int jj = 0; jj < 4; ++jj) {
        const int i = i0 + wr * 32 + mr * 16 + lq * 4 + jj;
        const int d = wc * 32 + nc * 16 + l16;
        attn_out[((size_t)(b * SS + i)) * HID + h * HD + d] = f2h(acc[mr][nc][jj]);
      }
}

// ---------------------------------------------------------------------------
// Residual + LayerNorm
// ---------------------------------------------------------------------------
__global__ __launch_bounds__(256) void ln_kernel(const float* __restrict__ proj,
                                                 const float* __restrict__ query,
                                                 const float* __restrict__ gamma,
                                                 const float* __restrict__ beta,
                                                 float* __restrict__ out) {
  const int row = blockIdx.x;
  const int tid = threadIdx.x;

  float x[2];
  float sum = 0.f, sumsq = 0.f;
#pragma unroll
  for (int t = 0; t < 2; ++t) {
    const int c = tid + t * 256;
    float v = proj[(size_t)row * HID + c] + query[(size_t)row * HID + c];
    x[t] = v;
    sum += v;
    sumsq += v * v;
  }
#pragma unroll
  for (int off = 1; off < 64; off <<= 1) {
    sum += __shfl_xor(sum, off);
    sumsq += __shfl_xor(sumsq, off);
  }
  __shared__ float s1[4], s2[4];
  if ((tid & 63) == 0) {
    s1[tid >> 6] = sum;
    s2[tid >> 6] = sumsq;
  }
  __syncthreads();
  sum = s1[0] + s1[1] + s1[2] + s1[3];
  sumsq = s2[0] + s2[1] + s2[2] + s2[3];
  const float mu = sum * (1.f / HID);
  const float var = sumsq * (1.f / HID) - mu * mu;
  const float rstd = rsqrtf(var + EPSV);
#pragma unroll
  for (int t = 0; t < 2; ++t) {
    const int c = tid + t * 256;
    out[(size_t)row * HID + c] = (x[t] - mu) * rstd * gamma[c] + beta[c];
  }
}

// ---------------------------------------------------------------------------
extern "C" void kernel_launch(void* const* d_in, const int* in_sizes, int n_in,
                              void* d_out, int out_size, void* d_ws, size_t ws_size,
                              hipStream_t stream) {
  const float* query = (const float*)d_in[0];
  const float* key = (const float*)d_in[1];
  const float* value = (const float*)d_in[2];
  const int* mask = (const int*)d_in[3];
  const float* Wq = (const float*)d_in[4];
  const float* bq = (const float*)d_in[5];
  const float* Wk = (const float*)d_in[6];
  const float* bk = (const float*)d_in[7];
  const float* Wv = (const float*)d_in[8];
  const float* bv = (const float*)d_in[9];
  const float* Wo = (const float*)d_in[10];
  const float* bo = (const float*)d_in[11];
  const float* temp = (const float*)d_in[12];
  const float* gamma = (const float*)d_in[13];
  const float* beta = (const float*)d_in[14];

  float* out_final = (float*)d_out;                     // (B,S,HID)
  float* attn = (float*)d_out + (size_t)BB * SS * HID;  // (B,H,S,S)

  // workspace layout (36.5 MB total)
  unsigned short* Qh = (unsigned short*)d_ws;    // u16fx [bh][s][d]  8MB
  unsigned short* Kh = Qh + QKV_ELEMS;           // u16fx [bh][s][d]  8MB
  unsigned short* Vt = Kh + QKV_ELEMS;           // f16 [bh][d][s]    8MB
  unsigned short* aout = Vt + QKV_ELEMS;         // f16 [b*s][512]    8MB
  float* stats = (float*)(aout + QKV_ELEMS);     // 2 * TOTROWS       0.5MB
  float* msnap = stats + 2 * TOTROWS;            // NJT * TOTROWS     4MB
  float* proj = (float*)d_ws;                    // f32, aliases Qh+Kh (16MB)

  const dim3 blk(256);
  const dim3 ggrid(HID / 128, NROWS / 128);  // 4 x 64

  gemm_f16<3, false><<<ggrid, blk, 0, stream>>>(query, Wq, bq, Qh);
  gemm_f16<3, false><<<ggrid, blk, 0, stream>>>(key, Wk, bk, Kh);
  gemm_f16<2, false><<<ggrid, blk, 0, stream>>>(value, Wv, bv, Vt);

  const dim3 sgrid(SS / 128, BB * NH);  // 16 x 32 (4-row micro-tile)
  scores_kernel<<<sgrid, dim3(512), 0, stream>>>(Qh, Kh, mask, temp, attn, stats, msnap);
  const dim3 pgrid(SS / 64, BB * NH);  // 32 x 32
  attn_pv_norm_kernel<<<pgrid, blk, 0, stream>>>(Vt, stats, msnap, attn, aout);

  gemm_f16<0, true><<<ggrid, blk, 0, stream>>>(aout, Wo, bo, proj);
  ln_kernel<<<NROWS, blk, 0, stream>>>(proj, query, gamma, beta, out_final);
}

// Round 14
// 637.571 us; speedup vs baseline: 1.2093x; 1.2093x over previous
//
#include <hip/hip_runtime.h>
#include <math.h>

#define BB 4
#define SS 2048
#define NH 8
#define HD 64
#define HID 512
#define EPSV 1e-5f

#define NROWS (BB * SS)                // 8192 (b,s) rows
#define QKV_ELEMS (BB * NH * SS * HD)  // 4,194,304
#define TOTROWS (BB * NH * SS)         // 65536 (b,h,s) rows
#define NJT 16                         // msnap granularity: 128-wide jtiles

typedef __attribute__((ext_vector_type(8))) short short8;
typedef __attribute__((ext_vector_type(4))) float f32x4;

__device__ __forceinline__ unsigned short f2h(float f) {
  _Float16 h = (_Float16)f;
  return __builtin_bit_cast(unsigned short, h);
}
__device__ __forceinline__ float h2f(unsigned short u) {
  return (float)__builtin_bit_cast(_Float16, u);
}

// SAD of 2 packed u16 with accumulate: acc += |a.h0-b.h0| + |a.h1-b.h1|.
// Q/K are u16 fixed-point: u = round((x+8)*4096); offsets cancel in the
// subtraction so acc = 4096 * sum|q-k| exactly.
__device__ __forceinline__ void sad2(unsigned qa, unsigned kb, unsigned& acc) {
  asm("v_sad_u16 %0, %1, %2, %0" : "+v"(acc) : "v"(qa), "v"(kb));
}

__device__ __forceinline__ unsigned pk_mul_f16(unsigned a, unsigned b) {
  unsigned r;
  asm("v_pk_mul_f16 %0, %1, %2" : "=v"(r) : "v"(a), "v"(b));
  return r;
}

// ---------------------------------------------------------------------------
// f16-MFMA GEMM: C = A(M x 512) @ W(512 x 512)^T + bias.
// 128x128 tile, 256 threads (4 waves, 2x2 quadrants of 64x64), K-step 32.
// AF16: A is f16 (ushort) in gmem; else f32 (converted during staging).
// MODE 0: C f32 [m][n].
// MODE 2: C f16 transposed per head [bh][d][s] (V -> PV B-operand).
// MODE 3: C u16 FIXED-POINT split-head [bh][s][d] (Q, K for SAD scores):
//         u = clamp(round((v + 8) * 4096), 0, 65535).
// ---------------------------------------------------------------------------
template <int MODE, bool AF16>
__global__ __launch_bounds__(256, 2) void gemm_f16(const void* __restrict__ Ain,
                                                   const float* __restrict__ W,
                                                   const float* __restrict__ bias,
                                                   void* __restrict__ Cout) {
  __shared__ unsigned short As[128][40];  // 32 k + 8 pad
  __shared__ unsigned short Ws[128][40];
  const int m0 = blockIdx.y * 128;
  const int n0 = blockIdx.x * 128;
  const int tid = threadIdx.x;
  const int lane = tid & 63;
  const int w = tid >> 6;
  const int wr = w >> 1;
  const int wc = w & 1;
  const int l16 = lane & 15;
  const int lq = lane >> 4;

  f32x4 acc[4][4];
#pragma unroll
  for (int mr = 0; mr < 4; ++mr)
#pragma unroll
    for (int nc = 0; nc < 4; ++nc) acc[mr][nc] = (f32x4)0.f;

  for (int k0 = 0; k0 < HID; k0 += 32) {
    __syncthreads();
    if (AF16) {
      const unsigned short* A = (const unsigned short*)Ain;
#pragma unroll
      for (int p = 0; p < 2; ++p) {
        int idx = tid + p * 256;
        int row = idx >> 2;
        int ch = (idx & 3) * 8;
        *(uint4*)&As[row][ch] = *(const uint4*)&A[(size_t)(m0 + row) * HID + k0 + ch];
      }
#pragma unroll
      for (int p = 0; p < 4; ++p) {
        int idx = tid + p * 256;
        int row = idx >> 3;
        int c4 = (idx & 7) * 4;
        float4 wv = *(const float4*)&W[(size_t)(n0 + row) * HID + k0 + c4];
        ushort4 wb = {f2h(wv.x), f2h(wv.y), f2h(wv.z), f2h(wv.w)};
        *(ushort4*)&Ws[row][c4] = wb;
      }
    } else {
      const float* A = (const float*)Ain;
#pragma unroll
      for (int p = 0; p < 4; ++p) {
        int idx = tid + p * 256;
        int row = idx >> 3;
        int c4 = (idx & 7) * 4;
        float4 av = *(const float4*)&A[(size_t)(m0 + row) * HID + k0 + c4];
        float4 wv = *(const float4*)&W[(size_t)(n0 + row) * HID + k0 + c4];
        ushort4 ab = {f2h(av.x), f2h(av.y), f2h(av.z), f2h(av.w)};
        ushort4 wb = {f2h(wv.x), f2h(wv.y), f2h(wv.z), f2h(wv.w)};
        *(ushort4*)&As[row][c4] = ab;
        *(ushort4*)&Ws[row][c4] = wb;
      }
    }
    __syncthreads();
    const int kb = lq * 8;
    short8 a[4], b[4];
#pragma unroll
    for (int mr = 0; mr < 4; ++mr)
      a[mr] = *(const short8*)&As[wr * 64 + mr * 16 + l16][kb];
#pragma unroll
    for (int nc = 0; nc < 4; ++nc)
      b[nc] = *(const short8*)&Ws[wc * 64 + nc * 16 + l16][kb];
#pragma unroll
    for (int mr = 0; mr < 4; ++mr)
#pragma unroll
      for (int nc = 0; nc < 4; ++nc)
        acc[mr][nc] = __builtin_amdgcn_mfma_f32_16x16x32_f16(a[mr], b[nc], acc[mr][nc], 0, 0, 0);
  }

#pragma unroll
  for (int nc = 0; nc < 4; ++nc) {
    const int n = n0 + wc * 64 + nc * 16 + l16;
    const float bv = bias[n];
#pragma unroll
    for (int mr = 0; mr < 4; ++mr) {
#pragma unroll
      for (int jj = 0; jj < 4; ++jj) {
        const int m = m0 + wr * 64 + mr * 16 + lq * 4 + jj;
        float v = acc[mr][nc][jj] + bv;
        if (MODE == 0) {
          ((float*)Cout)[(size_t)m * HID + n] = v;
        } else if (MODE == 2) {  // f16 [bh][d][s]
          const int b_ = m >> 11, s = m & (SS - 1);
          const int h = n >> 6, d = n & 63;
          ((unsigned short*)Cout)[(((size_t)(b_ * NH + h)) * HD + d) * SS + s] = f2h(v);
        } else {  // MODE 3: u16 fixed-point [bh][s][d]
          const int b_ = m >> 11, s = m & (SS - 1);
          const int h = n >> 6, d = n & 63;
          int u = (int)floorf(fmaf(v, 4096.f, 32768.5f));
          u = u < 0 ? 0 : (u > 65535 ? 65535 : u);
          ((unsigned short*)Cout)[(((size_t)(b_ * NH + h)) * SS + s) * HD + d] =
              (unsigned short)u;
        }
      }
    }
  }
}

// ---------------------------------------------------------------------------
// Scores pass: 128-row i-tile, 128-col j-tiles, 512 threads (8 waves).
// 4x8 micro-tile: thread (trow=tid>>4, cg=tid&15) owns rows
// {i0+trow+32*rr, rr=0..3}, cols {cg+16c, c=0..7}. Each kx LDS read feeds
// 16 SADs -> total LDS instructions halved vs the 2-row version.
// Q loaded per-k8 (q4[4] = 16 VGPR live, static indexing, re-read from
// L1/L2-hot global each k8) — the remat pattern the compiler chose in
// rounds 10-12; keeps live set ~75 regs, NO spill. unroll 2 on k8 stops
// the compiler from hoisting all 32 q loads back into registers.
// Writes p' = exp(s - m_running) f16 into the SECOND HALF of each attn row.
// ---------------------------------------------------------------------------
__global__ __launch_bounds__(512, 4) void scores_kernel(
    const unsigned short* __restrict__ Qh, const unsigned short* __restrict__ Kh,
    const int* __restrict__ mask, const float* __restrict__ temp,
    float* __restrict__ attn, float* __restrict__ stats,
    float* __restrict__ msnap) {
  __shared__ unsigned short Ks[128][72];  // 64 u16 + 8 pad (144B rows)
  __shared__ int Ms[128];

  const int bh = blockIdx.y;
  const int b = bh >> 3;
  const int h = bh & 7;
  const int i0 = blockIdx.x * 128;
  const int tid = threadIdx.x;
  const int trow = tid >> 4;  // 0..31
  const int cg = tid & 15;    // 0..15
  const float tscale = temp[h] * (1.0f / 4096.0f);  // dist = sad * 2^-12

  const unsigned short* Qb = Qh + (size_t)bh * SS * HD;
  const unsigned short* Kb = Kh + (size_t)bh * SS * HD;
  float* attn_b = attn + (size_t)bh * SS * SS;

  float m[4], sg[4];
#pragma unroll
  for (int rr = 0; rr < 4; ++rr) {
    m[rr] = -INFINITY;
    sg[rr] = 0.f;
  }

  for (int j0 = 0; j0 < SS; j0 += 128) {
    __syncthreads();  // protect Ks reads from previous iteration
// stage K tile: 128 x 64 u16 = 1024 uint4 chunks (2 per thread)
#pragma unroll
    for (int p = 0; p < 2; ++p) {
      int idx = tid + p * 512;
      int row = idx >> 3;
      int ch = (idx & 7) * 8;
      *(uint4*)&Ks[row][ch] = *(const uint4*)&Kb[(size_t)(j0 + row) * HD + ch];
    }
    if (tid < 128) Ms[tid] = mask[b * SS + j0 + tid];
    __syncthreads();

    unsigned d[4][8];
#pragma unroll
    for (int rr = 0; rr < 4; ++rr)
#pragma unroll
      for (int c = 0; c < 8; ++c) d[rr][c] = 0u;

// q loaded per-k8 (16 VGPR live), kx LDS read feeds 16 SADs.
// unroll 2: bounded load batching, no mass-hoist of q.
#pragma unroll 2
    for (int k8 = 0; k8 < 8; ++k8) {
      uint4 q4[4];
#pragma unroll
      for (int rr = 0; rr < 4; ++rr)
        q4[rr] = *(const uint4*)&Qb[(size_t)(i0 + trow + 32 * rr) * HD + k8 * 8];
#pragma unroll
      for (int c = 0; c < 8; ++c) {
        const uint4 kx = *(const uint4*)&Ks[cg + 16 * c][k8 * 8];
#pragma unroll
        for (int rr = 0; rr < 4; ++rr) {
          sad2(q4[rr].x, kx.x, d[rr][c]);
          sad2(q4[rr].y, kx.y, d[rr][c]);
          sad2(q4[rr].z, kx.z, d[rr][c]);
          sad2(q4[rr].w, kx.w, d[rr][c]);
        }
      }
    }

    int msk[8];
#pragma unroll
    for (int c = 0; c < 8; ++c) msk[c] = Ms[cg + 16 * c];

    const int jt = j0 >> 7;
#pragma unroll
    for (int rr = 0; rr < 4; ++rr) {
      float s[8];
      float rmax = -INFINITY;
#pragma unroll
      for (int c = 0; c < 8; ++c) {
        float sc = -(float)d[rr][c] * tscale;
        if (msk[c] == 0) sc = -1e9f;
        s[c] = sc;
        rmax = fmaxf(rmax, sc);
      }
// make row max uniform across the 16 cg lanes
#pragma unroll
      for (int off = 1; off < 16; off <<= 1) rmax = fmaxf(rmax, __shfl_xor(rmax, off));
      const float mnew = fmaxf(m[rr], rmax);
      const int i = i0 + trow + 32 * rr;
      unsigned short* arow = (unsigned short*)(attn_b + (size_t)i * SS);
      float psum = 0.f;
#pragma unroll
      for (int c = 0; c < 8; ++c) {
        float pv = __expf(s[c] - mnew);
        psum += pv;
        arow[2048 + j0 + cg + 16 * c] = f2h(pv);  // p' f16, 2nd half of row
      }
      sg[rr] = sg[rr] * __expf(m[rr] - mnew) + psum;
      m[rr] = mnew;
      if (cg == 0) msnap[((size_t)bh * NJT + jt) * SS + i] = mnew;
    }
  }

#pragma unroll
  for (int rr = 0; rr < 4; ++rr) {
    float ssum = sg[rr];
#pragma unroll
    for (int off = 1; off < 16; off <<= 1) ssum += __shfl_xor(ssum, off);
    if (cg == 0) {
      const int row = bh * SS + i0 + trow + 32 * rr;
      stats[2 * row] = m[rr];
      stats[2 * row + 1] = ssum;
    }
  }
}

// ---------------------------------------------------------------------------
// FUSED pv+norm: per j-tile, read p' f16 (from 2nd half of each attn row),
// p32 = h2f(p') * corr -> write final f32 attn columns in place;
// p16 = pk_mul(p', corr_f16) -> Ps for the PV MFMA -> aout f16.
// ---------------------------------------------------------------------------
__global__ __launch_bounds__(256, 4) void attn_pv_norm_kernel(
    const unsigned short* __restrict__ Vt, const float* __restrict__ stats,
    const float* __restrict__ msnap, float* __restrict__ attn,
    unsigned short* __restrict__ attn_out) {
  __shared__ unsigned short Ps[64][72];
  __shared__ unsigned short Vts[64][72];
  __shared__ float corr_s[64];

  const int bh = blockIdx.y;
  const int b = bh >> 3;
  const int h = bh & 7;
  const int i0 = blockIdx.x * 64;
  const int tid = threadIdx.x;
  const int lane = tid & 63;
  const int w = tid >> 6;
  const int wr = w >> 1;
  const int wc = w & 1;
  const int l16 = lane & 15;
  const int lq = lane >> 4;

  float* attn_b = attn + (size_t)bh * SS * SS;
  const unsigned short* Vtb = Vt + (size_t)bh * HD * SS;

  float mfin = 0.f, inv = 0.f;
  if (tid < 64) {
    const int row = bh * SS + i0 + tid;
    mfin = stats[2 * row];
    inv = 1.0f / stats[2 * row + 1];
  }

  f32x4 acc[2][2];
#pragma unroll
  for (int mr = 0; mr < 2; ++mr)
#pragma unroll
    for (int nc = 0; nc < 2; ++nc) acc[mr][nc] = (f32x4)0.f;

  for (int j0 = 0; j0 < SS; j0 += 64) {
    __syncthreads();  // protect prev-iter Ps/Vts reads
    if (tid < 64)
      corr_s[tid] =
          __expf(msnap[((size_t)bh * NJT + (j0 >> 7)) * SS + i0 + tid] - mfin) * inv;
    // stage Vt tile + issue p' loads (p' lives at ushort offset 2048+)
    uint4 pv[2];
#pragma unroll
    for (int p = 0; p < 2; ++p) {
      int idx = tid + p * 256;
      int row = idx >> 3;
      int ch = (idx & 7) * 8;
      *(uint4*)&Vts[row][ch] = *(const uint4*)&Vtb[(size_t)row * SS + j0 + ch];
      pv[p] = *(const uint4*)((const unsigned short*)(attn_b + (size_t)(i0 + row) * SS) +
                              2048 + j0 + ch);
    }
    __syncthreads();  // corr_s ready; all p' loads drained before f32 stores
// p16 = p' * corr (packed f16) -> Ps ; p32 = h2f(p') * corr -> attn f32
#pragma unroll
    for (int p = 0; p < 2; ++p) {
      int idx = tid + p * 256;
      int row = idx >> 3;
      int ch = (idx & 7) * 8;
      const float cr = corr_s[row];
      unsigned short cu = f2h(cr);
      unsigned c2 = (unsigned)cu | ((unsigned)cu << 16);
      uint4 r;
      r.x = pk_mul_f16(pv[p].x, c2);
      r.y = pk_mul_f16(pv[p].y, c2);
      r.z = pk_mul_f16(pv[p].z, c2);
      r.w = pk_mul_f16(pv[p].w, c2);
      *(uint4*)&Ps[row][ch] = r;
      float* orow = attn_b + (size_t)(i0 + row) * SS + j0 + ch;
      float4 o0 = {h2f((unsigned short)(pv[p].x)) * cr,
                   h2f((unsigned short)(pv[p].x >> 16)) * cr,
                   h2f((unsigned short)(pv[p].y)) * cr,
                   h2f((unsigned short)(pv[p].y >> 16)) * cr};
      float4 o1 = {h2f((unsigned short)(pv[p].z)) * cr,
                   h2f((unsigned short)(pv[p].z >> 16)) * cr,
                   h2f((unsigned short)(pv[p].w)) * cr,
                   h2f((unsigned short)(pv[p].w >> 16)) * cr};
      *(float4*)&orow[0] = o0;
      *(float4*)&orow[4] = o1;
    }
    __syncthreads();
// MFMA: out(64x64) += P(64x64) @ V(64x64)
#pragma unroll
    for (int ks = 0; ks < 2; ++ks) {
      const int kb = ks * 32 + lq * 8;
      short8 a[2], bf[2];
#pragma unroll
      for (int mr = 0; mr < 2; ++mr)
        a[mr] = *(const short8*)&Ps[wr * 32 + mr * 16 + l16][kb];
#pragma unroll
      for (int nc = 0; nc < 2; ++nc)
        bf[nc] = *(const short8*)&Vts[wc * 32 + nc * 16 + l16][kb];
#pragma unroll
      for (int mr = 0; mr < 2; ++mr)
#pragma unroll
        for (int nc = 0; nc < 2; ++nc)
          acc[mr][nc] = __builtin_amdgcn_mfma_f32_16x16x32_f16(a[mr], bf[nc], acc[mr][nc], 0, 0, 0);
    }
  }

// epilogue: f16 write [b, s, h*64 + d]
#pragma unroll
  for (int mr = 0; mr < 2; ++mr)
#pragma unroll
    for (int nc = 0; nc < 2; ++nc)
#pragma unroll
      for (int jj = 0; jj < 4; ++jj) {
        const int i = i0 + wr * 32 + mr * 16 + lq * 4 + jj;
        const int d = wc * 32 + nc * 16 + l16;
        attn_out[((size_t)(b * SS + i)) * HID + h * HD + d] = f2h(acc[mr][nc][jj]);
      }
}

// ---------------------------------------------------------------------------
// Residual + LayerNorm
// ---------------------------------------------------------------------------
__global__ __launch_bounds__(256) void ln_kernel(const float* __restrict__ proj,
                                                 const float* __restrict__ query,
                                                 const float* __restrict__ gamma,
                                                 const float* __restrict__ beta,
                                                 float* __restrict__ out) {
  const int row = blockIdx.x;
  const int tid = threadIdx.x;

  float x[2];
  float sum = 0.f, sumsq = 0.f;
#pragma unroll
  for (int t = 0; t < 2; ++t) {
    const int c = tid + t * 256;
    float v = proj[(size_t)row * HID + c] + query[(size_t)row * HID + c];
    x[t] = v;
    sum += v;
    sumsq += v * v;
  }
#pragma unroll
  for (int off = 1; off < 64; off <<= 1) {
    sum += __shfl_xor(sum, off);
    sumsq += __shfl_xor(sumsq, off);
  }
  __shared__ float s1[4], s2[4];
  if ((tid & 63) == 0) {
    s1[tid >> 6] = sum;
    s2[tid >> 6] = sumsq;
  }
  __syncthreads();
  sum = s1[0] + s1[1] + s1[2] + s1[3];
  sumsq = s2[0] + s2[1] + s2[2] + s2[3];
  const float mu = sum * (1.f / HID);
  const float var = sumsq * (1.f / HID) - mu * mu;
  const float rstd = rsqrtf(var + EPSV);
#pragma unroll
  for (int t = 0; t < 2; ++t) {
    const int c = tid + t * 256;
    out[(size_t)row * HID + c] = (x[t] - mu) * rstd * gamma[c] + beta[c];
  }
}

// ---------------------------------------------------------------------------
extern "C" void kernel_launch(void* const* d_in, const int* in_sizes, int n_in,
                              void* d_out, int out_size, void* d_ws, size_t ws_size,
                              hipStream_t stream) {
  const float* query = (const float*)d_in[0];
  const float* key = (const float*)d_in[1];
  const float* value = (const float*)d_in[2];
  const int* mask = (const int*)d_in[3];
  const float* Wq = (const float*)d_in[4];
  const float* bq = (const float*)d_in[5];
  const float* Wk = (const float*)d_in[6];
  const float* bk = (const float*)d_in[7];
  const float* Wv = (const float*)d_in[8];
  const float* bv = (const float*)d_in[9];
  const float* Wo = (const float*)d_in[10];
  const float* bo = (const float*)d_in[11];
  const float* temp = (const float*)d_in[12];
  const float* gamma = (const float*)d_in[13];
  const float* beta = (const float*)d_in[14];

  float* out_final = (float*)d_out;                     // (B,S,HID)
  float* attn = (float*)d_out + (size_t)BB * SS * HID;  // (B,H,S,S)

  // workspace layout (36.5 MB total)
  unsigned short* Qh = (unsigned short*)d_ws;    // u16fx [bh][s][d]  8MB
  unsigned short* Kh = Qh + QKV_ELEMS;           // u16fx [bh][s][d]  8MB
  unsigned short* Vt = Kh + QKV_ELEMS;           // f16 [bh][d][s]    8MB
  unsigned short* aout = Vt + QKV_ELEMS;         // f16 [b*s][512]    8MB
  float* stats = (float*)(aout + QKV_ELEMS);     // 2 * TOTROWS       0.5MB
  float* msnap = stats + 2 * TOTROWS;            // NJT * TOTROWS     4MB
  float* proj = (float*)d_ws;                    // f32, aliases Qh+Kh (16MB)

  const dim3 blk(256);
  const dim3 ggrid(HID / 128, NROWS / 128);  // 4 x 64

  gemm_f16<3, false><<<ggrid, blk, 0, stream>>>(query, Wq, bq, Qh);
  gemm_f16<3, false><<<ggrid, blk, 0, stream>>>(key, Wk, bk, Kh);
  gemm_f16<2, false><<<ggrid, blk, 0, stream>>>(value, Wv, bv, Vt);

  const dim3 sgrid(SS / 128, BB * NH);  // 16 x 32 (4-row micro-tile)
  scores_kernel<<<sgrid, dim3(512), 0, stream>>>(Qh, Kh, mask, temp, attn, stats, msnap);
  const dim3 pgrid(SS / 64, BB * NH);  // 32 x 32
  attn_pv_norm_kernel<<<pgrid, blk, 0, stream>>>(Vt, stats, msnap, attn, aout);

  gemm_f16<0, true><<<ggrid, blk, 0, stream>>>(aout, Wo, bo, proj);
  ln_kernel<<<NROWS, blk, 0, stream>>>(proj, query, gamma, beta, out_final);
}

// Round 15
// 556.878 us; speedup vs baseline: 1.3845x; 1.1449x over previous
//
#include <hip/hip_runtime.h>
#include <math.h>

#define BB 4
#define SS 2048
#define NH 8
#define HD 64
#define HID 512
#define EPSV 1e-5f

#define NROWS (BB * SS)                // 8192 (b,s) rows
#define QKV_ELEMS (BB * NH * SS * HD)  // 4,194,304
#define TOTROWS (BB * NH * SS)         // 65536 (b,h,s) rows
#define NJT 16                         // msnap granularity: 128-wide jtiles

typedef __attribute__((ext_vector_type(8))) short short8;
typedef __attribute__((ext_vector_type(4))) float f32x4;

__device__ __forceinline__ unsigned short f2h(float f) {
  _Float16 h = (_Float16)f;
  return __builtin_bit_cast(unsigned short, h);
}
__device__ __forceinline__ float h2f(unsigned short u) {
  return (float)__builtin_bit_cast(_Float16, u);
}

// SAD of 2 packed u16 with accumulate: acc += |a.h0-b.h0| + |a.h1-b.h1|.
// Q/K are u16 fixed-point: u = round((x+8)*4096); offsets cancel in the
// subtraction so acc = 4096 * sum|q-k| exactly.
__device__ __forceinline__ void sad2(unsigned qa, unsigned kb, unsigned& acc) {
  asm("v_sad_u16 %0, %1, %2, %0" : "+v"(acc) : "v"(qa), "v"(kb));
}

__device__ __forceinline__ unsigned pk_mul_f16(unsigned a, unsigned b) {
  unsigned r;
  asm("v_pk_mul_f16 %0, %1, %2" : "=v"(r) : "v"(a), "v"(b));
  return r;
}

// ---------------------------------------------------------------------------
// Merged QKV projection: one launch, blockIdx.z in {0:Q, 1:K, 2:V}.
// C = A(8192 x 512) @ W(512 x 512)^T + bias, 128x128 tile, 256 threads.
// z<2 : u16 fixed-point split-head [bh][s][d] (for SAD scores).
// z==2: f16 transposed per head [bh][d][s] (V -> PV B-operand).
// ---------------------------------------------------------------------------
__global__ __launch_bounds__(256, 2) void qkv_proj_kernel(
    const float* __restrict__ query, const float* __restrict__ key,
    const float* __restrict__ value, const float* __restrict__ Wq,
    const float* __restrict__ Wk, const float* __restrict__ Wv,
    const float* __restrict__ bq, const float* __restrict__ bk,
    const float* __restrict__ bv, unsigned short* __restrict__ Qh,
    unsigned short* __restrict__ Kh, unsigned short* __restrict__ Vt) {
  __shared__ unsigned short As[128][40];  // 32 k + 8 pad
  __shared__ unsigned short Ws[128][40];
  const int z = blockIdx.z;
  const float* A = (z == 0) ? query : (z == 1) ? key : value;
  const float* W = (z == 0) ? Wq : (z == 1) ? Wk : Wv;
  const float* bias = (z == 0) ? bq : (z == 1) ? bk : bv;
  unsigned short* Cout = (z == 0) ? Qh : (z == 1) ? Kh : Vt;

  const int m0 = blockIdx.y * 128;
  const int n0 = blockIdx.x * 128;
  const int tid = threadIdx.x;
  const int lane = tid & 63;
  const int w = tid >> 6;
  const int wr = w >> 1;
  const int wc = w & 1;
  const int l16 = lane & 15;
  const int lq = lane >> 4;

  f32x4 acc[4][4];
#pragma unroll
  for (int mr = 0; mr < 4; ++mr)
#pragma unroll
    for (int nc = 0; nc < 4; ++nc) acc[mr][nc] = (f32x4)0.f;

  for (int k0 = 0; k0 < HID; k0 += 32) {
    __syncthreads();
#pragma unroll
    for (int p = 0; p < 4; ++p) {
      int idx = tid + p * 256;
      int row = idx >> 3;
      int c4 = (idx & 7) * 4;
      float4 av = *(const float4*)&A[(size_t)(m0 + row) * HID + k0 + c4];
      float4 wv = *(const float4*)&W[(size_t)(n0 + row) * HID + k0 + c4];
      ushort4 ab = {f2h(av.x), f2h(av.y), f2h(av.z), f2h(av.w)};
      ushort4 wb = {f2h(wv.x), f2h(wv.y), f2h(wv.z), f2h(wv.w)};
      *(ushort4*)&As[row][c4] = ab;
      *(ushort4*)&Ws[row][c4] = wb;
    }
    __syncthreads();
    const int kb = lq * 8;
    short8 a[4], b[4];
#pragma unroll
    for (int mr = 0; mr < 4; ++mr)
      a[mr] = *(const short8*)&As[wr * 64 + mr * 16 + l16][kb];
#pragma unroll
    for (int nc = 0; nc < 4; ++nc)
      b[nc] = *(const short8*)&Ws[wc * 64 + nc * 16 + l16][kb];
#pragma unroll
    for (int mr = 0; mr < 4; ++mr)
#pragma unroll
      for (int nc = 0; nc < 4; ++nc)
        acc[mr][nc] = __builtin_amdgcn_mfma_f32_16x16x32_f16(a[mr], b[nc], acc[mr][nc], 0, 0, 0);
  }

#pragma unroll
  for (int nc = 0; nc < 4; ++nc) {
    const int n = n0 + wc * 64 + nc * 16 + l16;
    const float bv_ = bias[n];
#pragma unroll
    for (int mr = 0; mr < 4; ++mr) {
#pragma unroll
      for (int jj = 0; jj < 4; ++jj) {
        const int m = m0 + wr * 64 + mr * 16 + lq * 4 + jj;
        float v = acc[mr][nc][jj] + bv_;
        const int b_ = m >> 11, s = m & (SS - 1);
        const int h = n >> 6, d = n & 63;
        if (z == 2) {  // f16 [bh][d][s]
          Cout[(((size_t)(b_ * NH + h)) * HD + d) * SS + s] = f2h(v);
        } else {  // u16 fixed-point [bh][s][d]
          int u = (int)floorf(fmaf(v, 4096.f, 32768.5f));
          u = u < 0 ? 0 : (u > 65535 ? 65535 : u);
          Cout[(((size_t)(b_ * NH + h)) * SS + s) * HD + d] = (unsigned short)u;
        }
      }
    }
  }
}

// ---------------------------------------------------------------------------
// Output projection GEMM: C f32 [m][n] = A_f16(M x 512) @ W(512 x 512)^T + b.
// ---------------------------------------------------------------------------
__global__ __launch_bounds__(256, 2) void gemm_out(const unsigned short* __restrict__ A,
                                                   const float* __restrict__ W,
                                                   const float* __restrict__ bias,
                                                   float* __restrict__ Cout) {
  __shared__ unsigned short As[128][40];
  __shared__ unsigned short Ws[128][40];
  const int m0 = blockIdx.y * 128;
  const int n0 = blockIdx.x * 128;
  const int tid = threadIdx.x;
  const int lane = tid & 63;
  const int w = tid >> 6;
  const int wr = w >> 1;
  const int wc = w & 1;
  const int l16 = lane & 15;
  const int lq = lane >> 4;

  f32x4 acc[4][4];
#pragma unroll
  for (int mr = 0; mr < 4; ++mr)
#pragma unroll
    for (int nc = 0; nc < 4; ++nc) acc[mr][nc] = (f32x4)0.f;

  for (int k0 = 0; k0 < HID; k0 += 32) {
    __syncthreads();
#pragma unroll
    for (int p = 0; p < 2; ++p) {
      int idx = tid + p * 256;
      int row = idx >> 2;
      int ch = (idx & 3) * 8;
      *(uint4*)&As[row][ch] = *(const uint4*)&A[(size_t)(m0 + row) * HID + k0 + ch];
    }
#pragma unroll
    for (int p = 0; p < 4; ++p) {
      int idx = tid + p * 256;
      int row = idx >> 3;
      int c4 = (idx & 7) * 4;
      float4 wv = *(const float4*)&W[(size_t)(n0 + row) * HID + k0 + c4];
      ushort4 wb = {f2h(wv.x), f2h(wv.y), f2h(wv.z), f2h(wv.w)};
      *(ushort4*)&Ws[row][c4] = wb;
    }
    __syncthreads();
    const int kb = lq * 8;
    short8 a[4], b[4];
#pragma unroll
    for (int mr = 0; mr < 4; ++mr)
      a[mr] = *(const short8*)&As[wr * 64 + mr * 16 + l16][kb];
#pragma unroll
    for (int nc = 0; nc < 4; ++nc)
      b[nc] = *(const short8*)&Ws[wc * 64 + nc * 16 + l16][kb];
#pragma unroll
    for (int mr = 0; mr < 4; ++mr)
#pragma unroll
      for (int nc = 0; nc < 4; ++nc)
        acc[mr][nc] = __builtin_amdgcn_mfma_f32_16x16x32_f16(a[mr], b[nc], acc[mr][nc], 0, 0, 0);
  }

#pragma unroll
  for (int nc = 0; nc < 4; ++nc) {
    const int n = n0 + wc * 64 + nc * 16 + l16;
    const float bv = bias[n];
#pragma unroll
    for (int mr = 0; mr < 4; ++mr)
#pragma unroll
      for (int jj = 0; jj < 4; ++jj) {
        const int m = m0 + wr * 64 + mr * 16 + lq * 4 + jj;
        Cout[(size_t)m * HID + n] = acc[mr][nc][jj] + bv;
      }
  }
}

// ---------------------------------------------------------------------------
// Scores pass (round-14, at SAD floor): 128-row i-tile, 128-col j-tiles,
// 512 threads. 4x8 micro-tile; Q loaded per-k8 (L1-hot, static indexing).
// Writes p' = exp(s - m_running) f16 into the SECOND HALF of each attn row.
// ---------------------------------------------------------------------------
__global__ __launch_bounds__(512, 4) void scores_kernel(
    const unsigned short* __restrict__ Qh, const unsigned short* __restrict__ Kh,
    const int* __restrict__ mask, const float* __restrict__ temp,
    float* __restrict__ attn, float* __restrict__ stats,
    float* __restrict__ msnap) {
  __shared__ unsigned short Ks[128][72];  // 64 u16 + 8 pad (144B rows)
  __shared__ int Ms[128];

  const int bh = blockIdx.y;
  const int b = bh >> 3;
  const int h = bh & 7;
  const int i0 = blockIdx.x * 128;
  const int tid = threadIdx.x;
  const int trow = tid >> 4;  // 0..31
  const int cg = tid & 15;    // 0..15
  const float tscale = temp[h] * (1.0f / 4096.0f);  // dist = sad * 2^-12

  const unsigned short* Qb = Qh + (size_t)bh * SS * HD;
  const unsigned short* Kb = Kh + (size_t)bh * SS * HD;
  float* attn_b = attn + (size_t)bh * SS * SS;

  float m[4], sg[4];
#pragma unroll
  for (int rr = 0; rr < 4; ++rr) {
    m[rr] = -INFINITY;
    sg[rr] = 0.f;
  }

  for (int j0 = 0; j0 < SS; j0 += 128) {
    __syncthreads();  // protect Ks reads from previous iteration
#pragma unroll
    for (int p = 0; p < 2; ++p) {
      int idx = tid + p * 512;
      int row = idx >> 3;
      int ch = (idx & 7) * 8;
      *(uint4*)&Ks[row][ch] = *(const uint4*)&Kb[(size_t)(j0 + row) * HD + ch];
    }
    if (tid < 128) Ms[tid] = mask[b * SS + j0 + tid];
    __syncthreads();

    unsigned d[4][8];
#pragma unroll
    for (int rr = 0; rr < 4; ++rr)
#pragma unroll
      for (int c = 0; c < 8; ++c) d[rr][c] = 0u;

#pragma unroll 2
    for (int k8 = 0; k8 < 8; ++k8) {
      uint4 q4[4];
#pragma unroll
      for (int rr = 0; rr < 4; ++rr)
        q4[rr] = *(const uint4*)&Qb[(size_t)(i0 + trow + 32 * rr) * HD + k8 * 8];
#pragma unroll
      for (int c = 0; c < 8; ++c) {
        const uint4 kx = *(const uint4*)&Ks[cg + 16 * c][k8 * 8];
#pragma unroll
        for (int rr = 0; rr < 4; ++rr) {
          sad2(q4[rr].x, kx.x, d[rr][c]);
          sad2(q4[rr].y, kx.y, d[rr][c]);
          sad2(q4[rr].z, kx.z, d[rr][c]);
          sad2(q4[rr].w, kx.w, d[rr][c]);
        }
      }
    }

    int msk[8];
#pragma unroll
    for (int c = 0; c < 8; ++c) msk[c] = Ms[cg + 16 * c];

    const int jt = j0 >> 7;
#pragma unroll
    for (int rr = 0; rr < 4; ++rr) {
      float s[8];
      float rmax = -INFINITY;
#pragma unroll
      for (int c = 0; c < 8; ++c) {
        float sc = -(float)d[rr][c] * tscale;
        if (msk[c] == 0) sc = -1e9f;
        s[c] = sc;
        rmax = fmaxf(rmax, sc);
      }
#pragma unroll
      for (int off = 1; off < 16; off <<= 1) rmax = fmaxf(rmax, __shfl_xor(rmax, off));
      const float mnew = fmaxf(m[rr], rmax);
      const int i = i0 + trow + 32 * rr;
      unsigned short* arow = (unsigned short*)(attn_b + (size_t)i * SS);
      float psum = 0.f;
#pragma unroll
      for (int c = 0; c < 8; ++c) {
        float pv = __expf(s[c] - mnew);
        psum += pv;
        arow[2048 + j0 + cg + 16 * c] = f2h(pv);  // p' f16, 2nd half of row
      }
      sg[rr] = sg[rr] * __expf(m[rr] - mnew) + psum;
      m[rr] = mnew;
      if (cg == 0) msnap[((size_t)bh * NJT + jt) * SS + i] = mnew;
    }
  }

#pragma unroll
  for (int rr = 0; rr < 4; ++rr) {
    float ssum = sg[rr];
#pragma unroll
    for (int off = 1; off < 16; off <<= 1) ssum += __shfl_xor(ssum, off);
    if (cg == 0) {
      const int row = bh * SS + i0 + trow + 32 * rr;
      stats[2 * row] = m[rr];
      stats[2 * row + 1] = ssum;
    }
  }
}

// ---------------------------------------------------------------------------
// FUSED pv+norm: 128-row i-tile, 512 threads (8 waves, 4x2 wave grid).
// Per j-tile (64): read p' f16, p32 = h2f(p')*corr -> f32 attn in place;
// p16 = pk_mul(p', corr_f16) -> Ps -> PV MFMA -> aout f16.
// Safety: within-block ordering, p' loads precede f32 stores across barrier.
// ---------------------------------------------------------------------------
__global__ __launch_bounds__(512, 2) void attn_pv_norm_kernel(
    const unsigned short* __restrict__ Vt, const float* __restrict__ stats,
    const float* __restrict__ msnap, float* __restrict__ attn,
    unsigned short* __restrict__ attn_out) {
  __shared__ unsigned short Ps[128][72];
  __shared__ unsigned short Vts[64][72];
  __shared__ float corr_s[128];

  const int bh = blockIdx.y;
  const int b = bh >> 3;
  const int h = bh & 7;
  const int i0 = blockIdx.x * 128;
  const int tid = threadIdx.x;
  const int lane = tid & 63;
  const int w = tid >> 6;   // 0..7
  const int wr = w >> 1;    // 0..3 row-group
  const int wc = w & 1;     // d-half
  const int l16 = lane & 15;
  const int lq = lane >> 4;

  float* attn_b = attn + (size_t)bh * SS * SS;
  const unsigned short* Vtb = Vt + (size_t)bh * HD * SS;

  float mfin = 0.f, inv = 0.f;
  if (tid < 128) {
    const int row = bh * SS + i0 + tid;
    mfin = stats[2 * row];
    inv = 1.0f / stats[2 * row + 1];
  }

  f32x4 acc[2][2];
#pragma unroll
  for (int mr = 0; mr < 2; ++mr)
#pragma unroll
    for (int nc = 0; nc < 2; ++nc) acc[mr][nc] = (f32x4)0.f;

  for (int j0 = 0; j0 < SS; j0 += 64) {
    __syncthreads();  // protect prev-iter Ps/Vts reads
    if (tid < 128)
      corr_s[tid] =
          __expf(msnap[((size_t)bh * NJT + (j0 >> 7)) * SS + i0 + tid] - mfin) * inv;
    // stage Vt tile (512 uint4, 1/thread) + p' loads (1024 uint4, 2/thread)
    {
      int row = tid >> 3;
      int ch = (tid & 7) * 8;
      *(uint4*)&Vts[row][ch] = *(const uint4*)&Vtb[(size_t)row * SS + j0 + ch];
    }
    uint4 pv[2];
#pragma unroll
    for (int p = 0; p < 2; ++p) {
      int idx = tid + p * 512;
      int row = idx >> 3;  // 0..127
      int ch = (idx & 7) * 8;
      pv[p] = *(const uint4*)((const unsigned short*)(attn_b + (size_t)(i0 + row) * SS) +
                              2048 + j0 + ch);
    }
    __syncthreads();  // corr_s ready; all p' loads drained before f32 stores
#pragma unroll
    for (int p = 0; p < 2; ++p) {
      int idx = tid + p * 512;
      int row = idx >> 3;
      int ch = (idx & 7) * 8;
      const float cr = corr_s[row];
      unsigned short cu = f2h(cr);
      unsigned c2 = (unsigned)cu | ((unsigned)cu << 16);
      uint4 r;
      r.x = pk_mul_f16(pv[p].x, c2);
      r.y = pk_mul_f16(pv[p].y, c2);
      r.z = pk_mul_f16(pv[p].z, c2);
      r.w = pk_mul_f16(pv[p].w, c2);
      *(uint4*)&Ps[row][ch] = r;
      float* orow = attn_b + (size_t)(i0 + row) * SS + j0 + ch;
      float4 o0 = {h2f((unsigned short)(pv[p].x)) * cr,
                   h2f((unsigned short)(pv[p].x >> 16)) * cr,
                   h2f((unsigned short)(pv[p].y)) * cr,
                   h2f((unsigned short)(pv[p].y >> 16)) * cr};
      float4 o1 = {h2f((unsigned short)(pv[p].z)) * cr,
                   h2f((unsigned short)(pv[p].z >> 16)) * cr,
                   h2f((unsigned short)(pv[p].w)) * cr,
                   h2f((unsigned short)(pv[p].w >> 16)) * cr};
      *(float4*)&orow[0] = o0;
      *(float4*)&orow[4] = o1;
    }
    __syncthreads();
// MFMA: out(128x64) += P(128x64) @ V(64x64); wave w: rows wr*32+, d-half wc
#pragma unroll
    for (int ks = 0; ks < 2; ++ks) {
      const int kb = ks * 32 + lq * 8;
      short8 a[2], bf[2];
#pragma unroll
      for (int mr = 0; mr < 2; ++mr)
        a[mr] = *(const short8*)&Ps[wr * 32 + mr * 16 + l16][kb];
#pragma unroll
      for (int nc = 0; nc < 2; ++nc)
        bf[nc] = *(const short8*)&Vts[wc * 32 + nc * 16 + l16][kb];
#pragma unroll
      for (int mr = 0; mr < 2; ++mr)
#pragma unroll
        for (int nc = 0; nc < 2; ++nc)
          acc[mr][nc] = __builtin_amdgcn_mfma_f32_16x16x32_f16(a[mr], bf[nc], acc[mr][nc], 0, 0, 0);
    }
  }

// epilogue: f16 write [b, s, h*64 + d]
#pragma unroll
  for (int mr = 0; mr < 2; ++mr)
#pragma unroll
    for (int nc = 0; nc < 2; ++nc)
#pragma unroll
      for (int jj = 0; jj < 4; ++jj) {
        const int i = i0 + wr * 32 + mr * 16 + lq * 4 + jj;
        const int d = wc * 32 + nc * 16 + l16;
        attn_out[((size_t)(b * SS + i)) * HID + h * HD + d] = f2h(acc[mr][nc][jj]);
      }
}

// ---------------------------------------------------------------------------
// Residual + LayerNorm
// ---------------------------------------------------------------------------
__global__ __launch_bounds__(256) void ln_kernel(const float* __restrict__ proj,
                                                 const float* __restrict__ query,
                                                 const float* __restrict__ gamma,
                                                 const float* __restrict__ beta,
                                                 float* __restrict__ out) {
  const int row = blockIdx.x;
  const int tid = threadIdx.x;

  float x[2];
  float sum = 0.f, sumsq = 0.f;
#pragma unroll
  for (int t = 0; t < 2; ++t) {
    const int c = tid + t * 256;
    float v = proj[(size_t)row * HID + c] + query[(size_t)row * HID + c];
    x[t] = v;
    sum += v;
    sumsq += v * v;
  }
#pragma unroll
  for (int off = 1; off < 64; off <<= 1) {
    sum += __shfl_xor(sum, off);
    sumsq += __shfl_xor(sumsq, off);
  }
  __shared__ float s1[4], s2[4];
  if ((tid & 63) == 0) {
    s1[tid >> 6] = sum;
    s2[tid >> 6] = sumsq;
  }
  __syncthreads();
  sum = s1[0] + s1[1] + s1[2] + s1[3];
  sumsq = s2[0] + s2[1] + s2[2] + s2[3];
  const float mu = sum * (1.f / HID);
  const float var = sumsq * (1.f / HID) - mu * mu;
  const float rstd = rsqrtf(var + EPSV);
#pragma unroll
  for (int t = 0; t < 2; ++t) {
    const int c = tid + t * 256;
    out[(size_t)row * HID + c] = (x[t] - mu) * rstd * gamma[c] + beta[c];
  }
}

// ---------------------------------------------------------------------------
extern "C" void kernel_launch(void* const* d_in, const int* in_sizes, int n_in,
                              void* d_out, int out_size, void* d_ws, size_t ws_size,
                              hipStream_t stream) {
  const float* query = (const float*)d_in[0];
  const float* key = (const float*)d_in[1];
  const float* value = (const float*)d_in[2];
  const int* mask = (const int*)d_in[3];
  const float* Wq = (const float*)d_in[4];
  const float* bq = (const float*)d_in[5];
  const float* Wk = (const float*)d_in[6];
  const float* bk = (const float*)d_in[7];
  const float* Wv = (const float*)d_in[8];
  const float* bv = (const float*)d_in[9];
  const float* Wo = (const float*)d_in[10];
  const float* bo = (const float*)d_in[11];
  const float* temp = (const float*)d_in[12];
  const float* gamma = (const float*)d_in[13];
  const float* beta = (const float*)d_in[14];

  float* out_final = (float*)d_out;                     // (B,S,HID)
  float* attn = (float*)d_out + (size_t)BB * SS * HID;  // (B,H,S,S)

  // workspace layout (36.5 MB total)
  unsigned short* Qh = (unsigned short*)d_ws;    // u16fx [bh][s][d]  8MB
  unsigned short* Kh = Qh + QKV_ELEMS;           // u16fx [bh][s][d]  8MB
  unsigned short* Vt = Kh + QKV_ELEMS;           // f16 [bh][d][s]    8MB
  unsigned short* aout = Vt + QKV_ELEMS;         // f16 [b*s][512]    8MB
  float* stats = (float*)(aout + QKV_ELEMS);     // 2 * TOTROWS       0.5MB
  float* msnap = stats + 2 * TOTROWS;            // NJT * TOTROWS     4MB
  float* proj = (float*)d_ws;                    // f32, aliases Qh+Kh (16MB)

  const dim3 blk(256);

  // merged Q/K/V projections: one launch, 768 blocks
  qkv_proj_kernel<<<dim3(HID / 128, NROWS / 128, 3), blk, 0, stream>>>(
      query, key, value, Wq, Wk, Wv, bq, bk, bv, Qh, Kh, Vt);

  const dim3 sgrid(SS / 128, BB * NH);  // 16 x 32 (4-row micro-tile)
  scores_kernel<<<sgrid, dim3(512), 0, stream>>>(Qh, Kh, mask, temp, attn, stats, msnap);

  const dim3 pgrid(SS / 128, BB * NH);  // 16 x 32 (128-row i-tiles)
  attn_pv_norm_kernel<<<pgrid, dim3(512), 0, stream>>>(Vt, stats, msnap, attn, aout);

  gemm_out<<<dim3(HID / 128, NROWS / 128), blk, 0, stream>>>(aout, Wo, bo, proj);
  ln_kernel<<<NROWS, blk, 0, stream>>>(proj, query, gamma, beta, out_final);
}

// Round 16
// 483.134 us; speedup vs baseline: 1.5958x; 1.1526x over previous
//
#include <hip/hip_runtime.h>
#include <math.h>

#define BB 4
#define SS 2048
#define NH 8
#define HD 64
#define HID 512
#define EPSV 1e-5f

#define NROWS (BB * SS)                // 8192 (b,s) rows
#define QKV_ELEMS (BB * NH * SS * HD)  // 4,194,304
#define TOTROWS (BB * NH * SS)         // 65536 (b,h,s) rows
#define NJT 16                         // msnap granularity: 128-wide jtiles

typedef __attribute__((ext_vector_type(8))) short short8;
typedef __attribute__((ext_vector_type(4))) float f32x4;

__device__ __forceinline__ unsigned short f2h(float f) {
  _Float16 h = (_Float16)f;
  return __builtin_bit_cast(unsigned short, h);
}
__device__ __forceinline__ float h2f(unsigned short u) {
  return (float)__builtin_bit_cast(_Float16, u);
}

// SAD of 2 packed u16 with accumulate: acc += |a.h0-b.h0| + |a.h1-b.h1|.
// Q/K are u16 fixed-point: u = round((x+8)*4096); offsets cancel in the
// subtraction so acc = 4096 * sum|q-k| exactly.
__device__ __forceinline__ void sad2(unsigned qa, unsigned kb, unsigned& acc) {
  asm("v_sad_u16 %0, %1, %2, %0" : "+v"(acc) : "v"(qa), "v"(kb));
}

__device__ __forceinline__ unsigned pk_mul_f16(unsigned a, unsigned b) {
  unsigned r;
  asm("v_pk_mul_f16 %0, %1, %2" : "=v"(r) : "v"(a), "v"(b));
  return r;
}

// ---------------------------------------------------------------------------
// Merged QKV projection: one launch, blockIdx.z in {0:Q, 1:K, 2:V}.
// C = A(8192 x 512) @ W(512 x 512)^T + bias, 128x128 tile, 256 threads.
// z<2 : u16 fixed-point split-head [bh][s][d] (for SAD scores).
// z==2: f16 transposed per head [bh][d][s] (V -> PV B-operand).
// ---------------------------------------------------------------------------
__global__ __launch_bounds__(256, 2) void qkv_proj_kernel(
    const float* __restrict__ query, const float* __restrict__ key,
    const float* __restrict__ value, const float* __restrict__ Wq,
    const float* __restrict__ Wk, const float* __restrict__ Wv,
    const float* __restrict__ bq, const float* __restrict__ bk,
    const float* __restrict__ bv, unsigned short* __restrict__ Qh,
    unsigned short* __restrict__ Kh, unsigned short* __restrict__ Vt) {
  __shared__ unsigned short As[128][40];  // 32 k + 8 pad
  __shared__ unsigned short Ws[128][40];
  const int z = blockIdx.z;
  const float* A = (z == 0) ? query : (z == 1) ? key : value;
  const float* W = (z == 0) ? Wq : (z == 1) ? Wk : Wv;
  const float* bias = (z == 0) ? bq : (z == 1) ? bk : bv;
  unsigned short* Cout = (z == 0) ? Qh : (z == 1) ? Kh : Vt;

  const int m0 = blockIdx.y * 128;
  const int n0 = blockIdx.x * 128;
  const int tid = threadIdx.x;
  const int lane = tid & 63;
  const int w = tid >> 6;
  const int wr = w >> 1;
  const int wc = w & 1;
  const int l16 = lane & 15;
  const int lq = lane >> 4;

  f32x4 acc[4][4];
#pragma unroll
  for (int mr = 0; mr < 4; ++mr)
#pragma unroll
    for (int nc = 0; nc < 4; ++nc) acc[mr][nc] = (f32x4)0.f;

  for (int k0 = 0; k0 < HID; k0 += 32) {
    __syncthreads();
#pragma unroll
    for (int p = 0; p < 4; ++p) {
      int idx = tid + p * 256;
      int row = idx >> 3;
      int c4 = (idx & 7) * 4;
      float4 av = *(const float4*)&A[(size_t)(m0 + row) * HID + k0 + c4];
      float4 wv = *(const float4*)&W[(size_t)(n0 + row) * HID + k0 + c4];
      ushort4 ab = {f2h(av.x), f2h(av.y), f2h(av.z), f2h(av.w)};
      ushort4 wb = {f2h(wv.x), f2h(wv.y), f2h(wv.z), f2h(wv.w)};
      *(ushort4*)&As[row][c4] = ab;
      *(ushort4*)&Ws[row][c4] = wb;
    }
    __syncthreads();
    const int kb = lq * 8;
    short8 a[4], b[4];
#pragma unroll
    for (int mr = 0; mr < 4; ++mr)
      a[mr] = *(const short8*)&As[wr * 64 + mr * 16 + l16][kb];
#pragma unroll
    for (int nc = 0; nc < 4; ++nc)
      b[nc] = *(const short8*)&Ws[wc * 64 + nc * 16 + l16][kb];
#pragma unroll
    for (int mr = 0; mr < 4; ++mr)
#pragma unroll
      for (int nc = 0; nc < 4; ++nc)
        acc[mr][nc] = __builtin_amdgcn_mfma_f32_16x16x32_f16(a[mr], b[nc], acc[mr][nc], 0, 0, 0);
  }

#pragma unroll
  for (int nc = 0; nc < 4; ++nc) {
    const int n = n0 + wc * 64 + nc * 16 + l16;
    const float bv_ = bias[n];
#pragma unroll
    for (int mr = 0; mr < 4; ++mr) {
#pragma unroll
      for (int jj = 0; jj < 4; ++jj) {
        const int m = m0 + wr * 64 + mr * 16 + lq * 4 + jj;
        float v = acc[mr][nc][jj] + bv_;
        const int b_ = m >> 11, s = m & (SS - 1);
        const int h = n >> 6, d = n & 63;
        if (z == 2) {  // f16 [bh][d][s]
          Cout[(((size_t)(b_ * NH + h)) * HD + d) * SS + s] = f2h(v);
        } else {  // u16 fixed-point [bh][s][d]
          int u = (int)floorf(fmaf(v, 4096.f, 32768.5f));
          u = u < 0 ? 0 : (u > 65535 ? 65535 : u);
          Cout[(((size_t)(b_ * NH + h)) * SS + s) * HD + d] = (unsigned short)u;
        }
      }
    }
  }
}

// ---------------------------------------------------------------------------
// Output projection GEMM: C f32 [m][n] = A_f16(M x 512) @ W(512 x 512)^T + b.
// ---------------------------------------------------------------------------
__global__ __launch_bounds__(256, 2) void gemm_out(const unsigned short* __restrict__ A,
                                                   const float* __restrict__ W,
                                                   const float* __restrict__ bias,
                                                   float* __restrict__ Cout) {
  __shared__ unsigned short As[128][40];
  __shared__ unsigned short Ws[128][40];
  const int m0 = blockIdx.y * 128;
  const int n0 = blockIdx.x * 128;
  const int tid = threadIdx.x;
  const int lane = tid & 63;
  const int w = tid >> 6;
  const int wr = w >> 1;
  const int wc = w & 1;
  const int l16 = lane & 15;
  const int lq = lane >> 4;

  f32x4 acc[4][4];
#pragma unroll
  for (int mr = 0; mr < 4; ++mr)
#pragma unroll
    for (int nc = 0; nc < 4; ++nc) acc[mr][nc] = (f32x4)0.f;

  for (int k0 = 0; k0 < HID; k0 += 32) {
    __syncthreads();
#pragma unroll
    for (int p = 0; p < 2; ++p) {
      int idx = tid + p * 256;
      int row = idx >> 2;
      int ch = (idx & 3) * 8;
      *(uint4*)&As[row][ch] = *(const uint4*)&A[(size_t)(m0 + row) * HID + k0 + ch];
    }
#pragma unroll
    for (int p = 0; p < 4; ++p) {
      int idx = tid + p * 256;
      int row = idx >> 3;
      int c4 = (idx & 7) * 4;
      float4 wv = *(const float4*)&W[(size_t)(n0 + row) * HID + k0 + c4];
      ushort4 wb = {f2h(wv.x), f2h(wv.y), f2h(wv.z), f2h(wv.w)};
      *(ushort4*)&Ws[row][c4] = wb;
    }
    __syncthreads();
    const int kb = lq * 8;
    short8 a[4], b[4];
#pragma unroll
    for (int mr = 0; mr < 4; ++mr)
      a[mr] = *(const short8*)&As[wr * 64 + mr * 16 + l16][kb];
#pragma unroll
    for (int nc = 0; nc < 4; ++nc)
      b[nc] = *(const short8*)&Ws[wc * 64 + nc * 16 + l16][kb];
#pragma unroll
    for (int mr = 0; mr < 4; ++mr)
#pragma unroll
      for (int nc = 0; nc < 4; ++nc)
        acc[mr][nc] = __builtin_amdgcn_mfma_f32_16x16x32_f16(a[mr], b[nc], acc[mr][nc], 0, 0, 0);
  }

#pragma unroll
  for (int nc = 0; nc < 4; ++nc) {
    const int n = n0 + wc * 64 + nc * 16 + l16;
    const float bv = bias[n];
#pragma unroll
    for (int mr = 0; mr < 4; ++mr)
#pragma unroll
      for (int jj = 0; jj < 4; ++jj) {
        const int m = m0 + wr * 64 + mr * 16 + lq * 4 + jj;
        Cout[(size_t)m * HID + n] = acc[mr][nc][jj] + bv;
      }
  }
}

// ---------------------------------------------------------------------------
// FUSED attention: scores (SAD + online softmax, p' f16 to 2nd half of attn
// rows) THEN pv+norm (p32 in-place expansion + PV MFMA) for the same
// (bh, 128-row i-tile). stats/msnap live in LDS only. Safety: pv reads only
// this block's p' (written in phase 1, drained by barrier); f32 writes only
// this block's rows.
// ---------------------------------------------------------------------------
__global__ __launch_bounds__(512, 4) void attn_fused_kernel(
    const unsigned short* __restrict__ Qh, const unsigned short* __restrict__ Kh,
    const unsigned short* __restrict__ Vt, const int* __restrict__ mask,
    const float* __restrict__ temp, float* __restrict__ attn,
    unsigned short* __restrict__ attn_out) {
  __shared__ unsigned short KP[128][72];   // Ks in phase 1, Ps in phase 2
  __shared__ unsigned short Vts[64][72];
  __shared__ float msnap_s[NJT][128];
  __shared__ float mfin_s[128];
  __shared__ float inv_s[128];
  __shared__ float corr_s[128];
  __shared__ int Ms[128];

  const int bh = blockIdx.y;
  const int b = bh >> 3;
  const int h = bh & 7;
  const int i0 = blockIdx.x * 128;
  const int tid = threadIdx.x;
  const float tscale = temp[h] * (1.0f / 4096.0f);  // dist = sad * 2^-12

  const unsigned short* Qb = Qh + (size_t)bh * SS * HD;
  const unsigned short* Kb = Kh + (size_t)bh * SS * HD;
  const unsigned short* Vtb = Vt + (size_t)bh * HD * SS;
  float* attn_b = attn + (size_t)bh * SS * SS;

  // ========================= PHASE 1: scores =========================
  {
    const int trow = tid >> 4;  // 0..31
    const int cg = tid & 15;    // 0..15

    float m[4], sg[4];
#pragma unroll
    for (int rr = 0; rr < 4; ++rr) {
      m[rr] = -INFINITY;
      sg[rr] = 0.f;
    }

    for (int j0 = 0; j0 < SS; j0 += 128) {
      __syncthreads();  // protect Ks reads from previous iteration
#pragma unroll
      for (int p = 0; p < 2; ++p) {
        int idx = tid + p * 512;
        int row = idx >> 3;
        int ch = (idx & 7) * 8;
        *(uint4*)&KP[row][ch] = *(const uint4*)&Kb[(size_t)(j0 + row) * HD + ch];
      }
      if (tid < 128) Ms[tid] = mask[b * SS + j0 + tid];
      __syncthreads();

      unsigned d[4][8];
#pragma unroll
      for (int rr = 0; rr < 4; ++rr)
#pragma unroll
        for (int c = 0; c < 8; ++c) d[rr][c] = 0u;

#pragma unroll 2
      for (int k8 = 0; k8 < 8; ++k8) {
        uint4 q4[4];
#pragma unroll
        for (int rr = 0; rr < 4; ++rr)
          q4[rr] = *(const uint4*)&Qb[(size_t)(i0 + trow + 32 * rr) * HD + k8 * 8];
#pragma unroll
        for (int c = 0; c < 8; ++c) {
          const uint4 kx = *(const uint4*)&KP[cg + 16 * c][k8 * 8];
#pragma unroll
          for (int rr = 0; rr < 4; ++rr) {
            sad2(q4[rr].x, kx.x, d[rr][c]);
            sad2(q4[rr].y, kx.y, d[rr][c]);
            sad2(q4[rr].z, kx.z, d[rr][c]);
            sad2(q4[rr].w, kx.w, d[rr][c]);
          }
        }
      }

      int msk[8];
#pragma unroll
      for (int c = 0; c < 8; ++c) msk[c] = Ms[cg + 16 * c];

      const int jt = j0 >> 7;
#pragma unroll
      for (int rr = 0; rr < 4; ++rr) {
        float s[8];
        float rmax = -INFINITY;
#pragma unroll
        for (int c = 0; c < 8; ++c) {
          float sc = -(float)d[rr][c] * tscale;
          if (msk[c] == 0) sc = -1e9f;
          s[c] = sc;
          rmax = fmaxf(rmax, sc);
        }
#pragma unroll
        for (int off = 1; off < 16; off <<= 1)
          rmax = fmaxf(rmax, __shfl_xor(rmax, off));
        const float mnew = fmaxf(m[rr], rmax);
        const int i = i0 + trow + 32 * rr;
        unsigned short* arow = (unsigned short*)(attn_b + (size_t)i * SS);
        float psum = 0.f;
#pragma unroll
        for (int c = 0; c < 8; ++c) {
          float pv = __expf(s[c] - mnew);
          psum += pv;
          arow[2048 + j0 + cg + 16 * c] = f2h(pv);  // p' f16, 2nd half of row
        }
        sg[rr] = sg[rr] * __expf(m[rr] - mnew) + psum;
        m[rr] = mnew;
        if (cg == 0) msnap_s[jt][trow + 32 * rr] = mnew;
      }
    }

#pragma unroll
    for (int rr = 0; rr < 4; ++rr) {
      float ssum = sg[rr];
#pragma unroll
      for (int off = 1; off < 16; off <<= 1) ssum += __shfl_xor(ssum, off);
      if (cg == 0) {
        mfin_s[trow + 32 * rr] = m[rr];
        inv_s[trow + 32 * rr] = 1.0f / ssum;
      }
    }
  }

  __syncthreads();  // stats/msnap ready; p' global writes drained

  // ========================= PHASE 2: pv + norm =========================
  {
    const int lane = tid & 63;
    const int w = tid >> 6;  // 0..7
    const int wr = w >> 1;   // row-group
    const int wc = w & 1;    // d-half
    const int l16 = lane & 15;
    const int lq = lane >> 4;

    f32x4 acc[2][2];
#pragma unroll
    for (int mr = 0; mr < 2; ++mr)
#pragma unroll
      for (int nc = 0; nc < 2; ++nc) acc[mr][nc] = (f32x4)0.f;

    for (int j0 = 0; j0 < SS; j0 += 64) {
      __syncthreads();  // protect prev-iter Ps/Vts reads (and phase-1 KP)
      if (tid < 128)
        corr_s[tid] = __expf(msnap_s[j0 >> 7][tid] - mfin_s[tid]) * inv_s[tid];
      // stage Vt tile (512 uint4, 1/thread) + p' loads (1024 uint4, 2/thread)
      {
        int row = tid >> 3;
        int ch = (tid & 7) * 8;
        *(uint4*)&Vts[row][ch] = *(const uint4*)&Vtb[(size_t)row * SS + j0 + ch];
      }
      uint4 pv[2];
#pragma unroll
      for (int p = 0; p < 2; ++p) {
        int idx = tid + p * 512;
        int row = idx >> 3;  // 0..127
        int ch = (idx & 7) * 8;
        pv[p] = *(const uint4*)((const unsigned short*)(attn_b +
                                                        (size_t)(i0 + row) * SS) +
                                2048 + j0 + ch);
      }
      __syncthreads();  // corr_s ready; p' loads drained before f32 stores
#pragma unroll
      for (int p = 0; p < 2; ++p) {
        int idx = tid + p * 512;
        int row = idx >> 3;
        int ch = (idx & 7) * 8;
        const float cr = corr_s[row];
        unsigned short cu = f2h(cr);
        unsigned c2 = (unsigned)cu | ((unsigned)cu << 16);
        uint4 r;
        r.x = pk_mul_f16(pv[p].x, c2);
        r.y = pk_mul_f16(pv[p].y, c2);
        r.z = pk_mul_f16(pv[p].z, c2);
        r.w = pk_mul_f16(pv[p].w, c2);
        *(uint4*)&KP[row][ch] = r;
        float* orow = attn_b + (size_t)(i0 + row) * SS + j0 + ch;
        float4 o0 = {h2f((unsigned short)(pv[p].x)) * cr,
                     h2f((unsigned short)(pv[p].x >> 16)) * cr,
                     h2f((unsigned short)(pv[p].y)) * cr,
                     h2f((unsigned short)(pv[p].y >> 16)) * cr};
        float4 o1 = {h2f((unsigned short)(pv[p].z)) * cr,
                     h2f((unsigned short)(pv[p].z >> 16)) * cr,
                     h2f((unsigned short)(pv[p].w)) * cr,
                     h2f((unsigned short)(pv[p].w >> 16)) * cr};
        *(float4*)&orow[0] = o0;
        *(float4*)&orow[4] = o1;
      }
      __syncthreads();
// MFMA: out(128x64) += P(128x64) @ V(64x64); wave w: rows wr*32+, d-half wc
#pragma unroll
      for (int ks = 0; ks < 2; ++ks) {
        const int kb = ks * 32 + lq * 8;
        short8 a[2], bf[2];
#pragma unroll
        for (int mr = 0; mr < 2; ++mr)
          a[mr] = *(const short8*)&KP[wr * 32 + mr * 16 + l16][kb];
#pragma unroll
        for (int nc = 0; nc < 2; ++nc)
          bf[nc] = *(const short8*)&Vts[wc * 32 + nc * 16 + l16][kb];
#pragma unroll
        for (int mr = 0; mr < 2; ++mr)
#pragma unroll
          for (int nc = 0; nc < 2; ++nc)
            acc[mr][nc] =
                __builtin_amdgcn_mfma_f32_16x16x32_f16(a[mr], bf[nc], acc[mr][nc], 0, 0, 0);
      }
    }

// epilogue: f16 write [b, s, h*64 + d]
#pragma unroll
    for (int mr = 0; mr < 2; ++mr)
#pragma unroll
      for (int nc = 0; nc < 2; ++nc)
#pragma unroll
        for (int jj = 0; jj < 4; ++jj) {
          const int i = i0 + wr * 32 + mr * 16 + lq * 4 + jj;
          const int d = wc * 32 + nc * 16 + l16;
          attn_out[((size_t)(b * SS + i)) * HID + h * HD + d] = f2h(acc[mr][nc][jj]);
        }
  }
}

// ---------------------------------------------------------------------------
// Residual + LayerNorm
// ---------------------------------------------------------------------------
__global__ __launch_bounds__(256) void ln_kernel(const float* __restrict__ proj,
                                                 const float* __restrict__ query,
                                                 const float* __restrict__ gamma,
                                                 const float* __restrict__ beta,
                                                 float* __restrict__ out) {
  const int row = blockIdx.x;
  const int tid = threadIdx.x;

  float x[2];
  float sum = 0.f, sumsq = 0.f;
#pragma unroll
  for (int t = 0; t < 2; ++t) {
    const int c = tid + t * 256;
    float v = proj[(size_t)row * HID + c] + query[(size_t)row * HID + c];
    x[t] = v;
    sum += v;
    sumsq += v * v;
  }
#pragma unroll
  for (int off = 1; off < 64; off <<= 1) {
    sum += __shfl_xor(sum, off);
    sumsq += __shfl_xor(sumsq, off);
  }
  __shared__ float s1[4], s2[4];
  if ((tid & 63) == 0) {
    s1[tid >> 6] = sum;
    s2[tid >> 6] = sumsq;
  }
  __syncthreads();
  sum = s1[0] + s1[1] + s1[2] + s1[3];
  sumsq = s2[0] + s2[1] + s2[2] + s2[3];
  const float mu = sum * (1.f / HID);
  const float var = sumsq * (1.f / HID) - mu * mu;
  const float rstd = rsqrtf(var + EPSV);
#pragma unroll
  for (int t = 0; t < 2; ++t) {
    const int c = tid + t * 256;
    out[(size_t)row * HID + c] = (x[t] - mu) * rstd * gamma[c] + beta[c];
  }
}

// ---------------------------------------------------------------------------
extern "C" void kernel_launch(void* const* d_in, const int* in_sizes, int n_in,
                              void* d_out, int out_size, void* d_ws, size_t ws_size,
                              hipStream_t stream) {
  const float* query = (const float*)d_in[0];
  const float* key = (const float*)d_in[1];
  const float* value = (const float*)d_in[2];
  const int* mask = (const int*)d_in[3];
  const float* Wq = (const float*)d_in[4];
  const float* bq = (const float*)d_in[5];
  const float* Wk = (const float*)d_in[6];
  const float* bk = (const float*)d_in[7];
  const float* Wv = (const float*)d_in[8];
  const float* bv = (const float*)d_in[9];
  const float* Wo = (const float*)d_in[10];
  const float* bo = (const float*)d_in[11];
  const float* temp = (const float*)d_in[12];
  const float* gamma = (const float*)d_in[13];
  const float* beta = (const float*)d_in[14];

  float* out_final = (float*)d_out;                     // (B,S,HID)
  float* attn = (float*)d_out + (size_t)BB * SS * HID;  // (B,H,S,S)

  // workspace layout (32 MB used)
  unsigned short* Qh = (unsigned short*)d_ws;    // u16fx [bh][s][d]  8MB
  unsigned short* Kh = Qh + QKV_ELEMS;           // u16fx [bh][s][d]  8MB
  unsigned short* Vt = Kh + QKV_ELEMS;           // f16 [bh][d][s]    8MB
  unsigned short* aout = Vt + QKV_ELEMS;         // f16 [b*s][512]    8MB
  float* proj = (float*)d_ws;                    // f32, aliases Qh+Kh (16MB)

  const dim3 blk(256);

  // merged Q/K/V projections: one launch, 768 blocks
  qkv_proj_kernel<<<dim3(HID / 128, NROWS / 128, 3), blk, 0, stream>>>(
      query, key, value, Wq, Wk, Wv, bq, bk, bv, Qh, Kh, Vt);

  // fused scores + pv + norm: one launch, 512 blocks
  attn_fused_kernel<<<dim3(SS / 128, BB * NH), dim3(512), 0, stream>>>(
      Qh, Kh, Vt, mask, temp, attn, aout);

  gemm_out<<<dim3(HID / 128, NROWS / 128), blk, 0, stream>>>(aout, Wo, bo, proj);
  ln_kernel<<<NROWS, blk, 0, stream>>>(proj, query, gamma, beta, out_final);
}